// Round 1
// baseline (273.931 us; speedup 1.0000x reference)
//
#include <hip/hip_runtime.h>
#include <hip/hip_bf16.h>

// Problem constants (reference: N=16384, F=1024, H=256)
#define NR 16384
#define NF 1024
#define NH 256

typedef __bf16 bf16x8 __attribute__((ext_vector_type(8)));
typedef float f32x4 __attribute__((ext_vector_type(4)));
typedef unsigned short us8 __attribute__((ext_vector_type(8)));

__device__ __forceinline__ unsigned short f2bf(float f) {
    unsigned u = __float_as_uint(f);
    u += 0x7FFFu + ((u >> 16) & 1u);   // RNE
    return (unsigned short)(u >> 16);
}
__device__ __forceinline__ float bf2f(unsigned short h) {
    return __uint_as_float(((unsigned)h) << 16);
}

// ---------------------------------------------------------------------------
// prep: WeT[n][k] = bf16(We[k][n])  (256x1024), WdT[n][k] = bf16(Wd[k][n]) (1024x256)
// ---------------------------------------------------------------------------
__global__ __launch_bounds__(256) void prep_kernel(
    const float* __restrict__ We, const float* __restrict__ Wd,
    unsigned short* __restrict__ WeT, unsigned short* __restrict__ WdT) {
    int tid = blockIdx.x * 256 + threadIdx.x;
    if (tid < NH * NF) {
        int n = tid >> 10, k = tid & (NF - 1);
        WeT[tid] = f2bf(We[(size_t)k * NH + n]);
    } else {
        int t2 = tid - NH * NF;
        int n = t2 >> 8, k = t2 & (NH - 1);
        WdT[t2] = f2bf(Wd[(size_t)k * NF + n]);
    }
}

// ---------------------------------------------------------------------------
// GEMM1: g[16384][256] (bf16) = X (fp32, convert in-kernel) @ We (via WeT bf16) + be
// tile 128x128, 256 threads (4 waves, each 64x64 = 4x4 MFMA 16x16x32 tiles)
// ---------------------------------------------------------------------------
__global__ __launch_bounds__(256) void gemm1_kernel(
    const float* __restrict__ X, const unsigned short* __restrict__ Bt,
    const float* __restrict__ be, unsigned short* __restrict__ g) {
    __shared__ unsigned short As[128 * 40];  // [m][k], stride 40 (pad) bf16
    __shared__ unsigned short Bs[128 * 40];  // [n][k]
    const int t = threadIdx.x;
    const int m0 = blockIdx.x * 128;   // x = m-tile so n-blocks of same m are 128 apart (same XCD)
    const int n0 = blockIdx.y * 128;
    const int r = t >> 1, h = t & 1;
    const int wave = t >> 6, lane = t & 63;
    const int wr = (wave >> 1) * 64, wc = (wave & 1) * 64;
    const int q = lane >> 4, li = lane & 15;

    f32x4 acc[4][4];
#pragma unroll
    for (int i = 0; i < 4; i++)
#pragma unroll
        for (int j = 0; j < 4; j++) acc[i][j] = (f32x4){0.f, 0.f, 0.f, 0.f};

    for (int k0 = 0; k0 < NF; k0 += 32) {
        // stage A: X[m0+r][k0 + h*16 .. +15] fp32 -> bf16
        const float4* xp = reinterpret_cast<const float4*>(X + (size_t)(m0 + r) * NF + k0 + h * 16);
        float4 v0 = xp[0], v1 = xp[1], v2 = xp[2], v3 = xp[3];
        us8 pa, pb;
        pa[0] = f2bf(v0.x); pa[1] = f2bf(v0.y); pa[2] = f2bf(v0.z); pa[3] = f2bf(v0.w);
        pa[4] = f2bf(v1.x); pa[5] = f2bf(v1.y); pa[6] = f2bf(v1.z); pa[7] = f2bf(v1.w);
        pb[0] = f2bf(v2.x); pb[1] = f2bf(v2.y); pb[2] = f2bf(v2.z); pb[3] = f2bf(v2.w);
        pb[4] = f2bf(v3.x); pb[5] = f2bf(v3.y); pb[6] = f2bf(v3.z); pb[7] = f2bf(v3.w);
        *(us8*)&As[r * 40 + h * 16] = pa;
        *(us8*)&As[r * 40 + h * 16 + 8] = pb;
        // stage B: WeT[n0+r][k0 + h*16 .. +15] bf16 raw copy
        const uint4* bp = reinterpret_cast<const uint4*>(Bt + (size_t)(n0 + r) * NF + k0 + h * 16);
        uint4 b0 = bp[0], b1 = bp[1];
        *(uint4*)&Bs[r * 40 + h * 16] = b0;
        *(uint4*)&Bs[r * 40 + h * 16 + 8] = b1;
        __syncthreads();

        bf16x8 af[4], bfv[4];
#pragma unroll
        for (int i = 0; i < 4; i++)
            af[i] = __builtin_bit_cast(bf16x8, *(const us8*)&As[(wr + i * 16 + li) * 40 + q * 8]);
#pragma unroll
        for (int j = 0; j < 4; j++)
            bfv[j] = __builtin_bit_cast(bf16x8, *(const us8*)&Bs[(wc + j * 16 + li) * 40 + q * 8]);
#pragma unroll
        for (int i = 0; i < 4; i++)
#pragma unroll
            for (int j = 0; j < 4; j++)
                acc[i][j] = __builtin_amdgcn_mfma_f32_16x16x32_bf16(af[i], bfv[j], acc[i][j], 0, 0, 0);
        __syncthreads();
    }

    float bev[4];
#pragma unroll
    for (int j = 0; j < 4; j++) bev[j] = be[n0 + wc + j * 16 + li];
#pragma unroll
    for (int i = 0; i < 4; i++)
#pragma unroll
        for (int j = 0; j < 4; j++)
#pragma unroll
            for (int rg = 0; rg < 4; rg++) {
                int row = m0 + wr + i * 16 + q * 4 + rg;   // D: row=(lane>>4)*4+reg
                int col = n0 + wc + j * 16 + li;           //    col=lane&15
                g[(size_t)row * NH + col] = f2bf(acc[i][j][rg] + bev[j]);
            }
}

// ---------------------------------------------------------------------------
// GEMM2 fused with MSE: rec = g @ Wd + bd; accumulate sum((rec - X)^2); no rec store
// ---------------------------------------------------------------------------
__global__ __launch_bounds__(256) void gemm2_kernel(
    const unsigned short* __restrict__ g, const unsigned short* __restrict__ Bt,
    const float* __restrict__ bd, const float* __restrict__ X,
    float* __restrict__ mse_acc) {
    __shared__ unsigned short As[128 * 40];
    __shared__ unsigned short Bs[128 * 40];
    const int t = threadIdx.x;
    const int m0 = blockIdx.x * 128;
    const int n0 = blockIdx.y * 128;
    const int r = t >> 1, h = t & 1;
    const int wave = t >> 6, lane = t & 63;
    const int wr = (wave >> 1) * 64, wc = (wave & 1) * 64;
    const int q = lane >> 4, li = lane & 15;

    f32x4 acc[4][4];
#pragma unroll
    for (int i = 0; i < 4; i++)
#pragma unroll
        for (int j = 0; j < 4; j++) acc[i][j] = (f32x4){0.f, 0.f, 0.f, 0.f};

    for (int k0 = 0; k0 < NH; k0 += 32) {
        const uint4* ap = reinterpret_cast<const uint4*>(g + (size_t)(m0 + r) * NH + k0 + h * 16);
        uint4 a0 = ap[0], a1 = ap[1];
        *(uint4*)&As[r * 40 + h * 16] = a0;
        *(uint4*)&As[r * 40 + h * 16 + 8] = a1;
        const uint4* bp = reinterpret_cast<const uint4*>(Bt + (size_t)(n0 + r) * NH + k0 + h * 16);
        uint4 b0 = bp[0], b1 = bp[1];
        *(uint4*)&Bs[r * 40 + h * 16] = b0;
        *(uint4*)&Bs[r * 40 + h * 16 + 8] = b1;
        __syncthreads();

        bf16x8 af[4], bfv[4];
#pragma unroll
        for (int i = 0; i < 4; i++)
            af[i] = __builtin_bit_cast(bf16x8, *(const us8*)&As[(wr + i * 16 + li) * 40 + q * 8]);
#pragma unroll
        for (int j = 0; j < 4; j++)
            bfv[j] = __builtin_bit_cast(bf16x8, *(const us8*)&Bs[(wc + j * 16 + li) * 40 + q * 8]);
#pragma unroll
        for (int i = 0; i < 4; i++)
#pragma unroll
            for (int j = 0; j < 4; j++)
                acc[i][j] = __builtin_amdgcn_mfma_f32_16x16x32_bf16(af[i], bfv[j], acc[i][j], 0, 0, 0);
        __syncthreads();
    }

    float bdv[4];
#pragma unroll
    for (int j = 0; j < 4; j++) bdv[j] = bd[n0 + wc + j * 16 + li];
    float lsum = 0.f;
#pragma unroll
    for (int i = 0; i < 4; i++)
#pragma unroll
        for (int j = 0; j < 4; j++)
#pragma unroll
            for (int rg = 0; rg < 4; rg++) {
                int row = m0 + wr + i * 16 + q * 4 + rg;
                int col = n0 + wc + j * 16 + li;
                float rec = acc[i][j][rg] + bdv[j];
                float x = X[(size_t)row * NF + col];
                float d = rec - x;
                lsum += d * d;
            }
#pragma unroll
    for (int o = 32; o; o >>= 1) lsum += __shfl_down(lsum, o);
    if (lane == 0) atomicAdd(mse_acc, lsum);
}

// ---------------------------------------------------------------------------
// c = g @ Wc + bc   (one wave per row)
// ---------------------------------------------------------------------------
__global__ __launch_bounds__(256) void c_kernel(
    const unsigned short* __restrict__ g, const float* __restrict__ Wc,
    const float* __restrict__ bc, float* __restrict__ c) {
    int row = blockIdx.x * 4 + (threadIdx.x >> 6);
    int lane = threadIdx.x & 63;
    const ushort4 gv = *(const ushort4*)(g + (size_t)row * NH + lane * 4);
    const float4 wv = *(const float4*)(Wc + lane * 4);
    float s = bf2f(gv.x) * wv.x + bf2f(gv.y) * wv.y + bf2f(gv.z) * wv.z + bf2f(gv.w) * wv.w;
#pragma unroll
    for (int o = 32; o; o >>= 1) s += __shfl_down(s, o);
    if (lane == 0) c[row] = s + bc[0];
}

// ---------------------------------------------------------------------------
// compaction: cP = c[s==p], cR = c[s!=p] (order-free), wave-aggregated atomics
// ---------------------------------------------------------------------------
__global__ __launch_bounds__(256) void compact_kernel(
    const float* __restrict__ c, const int* __restrict__ s, const int* __restrict__ pv,
    float* __restrict__ cP, float* __restrict__ cR, int* __restrict__ cnt) {
    int i = blockIdx.x * 256 + threadIdx.x;
    float ci = c[i];
    bool pr = (s[i] == pv[0]);
    int lane = threadIdx.x & 63;
    unsigned long long m = __ballot(pr);
    {
        int cm = __popcll(m);
        int base = 0;
        if (lane == 0 && cm) base = atomicAdd(&cnt[0], cm);
        base = __shfl(base, 0);
        int off = __popcll(m & ((1ull << lane) - 1ull));
        if (pr) cP[base + off] = ci;
    }
    {
        unsigned long long mm = ~m;
        int cm = __popcll(mm);
        int base = 0;
        if (lane == 0 && cm) base = atomicAdd(&cnt[1], cm);
        base = __shfl(base, 0);
        int off = __popcll(mm & ((1ull << lane) - 1ull));
        if (!pr) cR[base + off] = ci;
    }
}

// ---------------------------------------------------------------------------
// pairwise masked L1: total += sum_{a in P, b in R} |cP[a] - cR[b]|
// grid (16 j-chunks of 1024, 64 i-chunks of 256)
// ---------------------------------------------------------------------------
__global__ __launch_bounds__(256) void pair_kernel(
    const float* __restrict__ cP, const float* __restrict__ cR,
    const int* __restrict__ cnt, float* __restrict__ total) {
    __shared__ float sj[1024];
    int nP = cnt[0], nR = cnt[1];
    int jb = blockIdx.x * 1024;
    int jn = nR - jb;
    if (jn > 1024) jn = 1024;
    for (int j = threadIdx.x; j < 1024; j += 256) {
        int jj = jb + j;
        sj[j] = (jj < nR) ? cR[jj] : 0.f;
    }
    __syncthreads();
    int a = blockIdx.y * 256 + threadIdx.x;
    float sum = 0.f;
    if (a < nP && jn > 0) {
        float ca = cP[a];
#pragma unroll 8
        for (int j = 0; j < jn; ++j) sum += fabsf(ca - sj[j]);
    }
#pragma unroll
    for (int o = 32; o; o >>= 1) sum += __shfl_down(sum, o);
    if ((threadIdx.x & 63) == 0 && sum != 0.f) atomicAdd(total, sum);
}

// ---------------------------------------------------------------------------
// finalize: write the 4 scalar outputs
// ---------------------------------------------------------------------------
__global__ void finalize_kernel(const float* __restrict__ accf, const int* __restrict__ acci,
                                float* __restrict__ out) {
    out[0] = accf[0] / (float)((size_t)NR * NF);  // mse mean
    out[1] = (float)NR;                           // rec.shape[0]
    int np = acci[2];
    out[2] = accf[1] / (float)np;                 // w_dist_mean
    out[3] = (float)np;                           // w_dist_count
}

extern "C" void kernel_launch(void* const* d_in, const int* in_sizes, int n_in,
                              void* d_out, int out_size, void* d_ws, size_t ws_size,
                              hipStream_t stream) {
    const float* X  = (const float*)d_in[0];
    const float* We = (const float*)d_in[1];
    const float* be = (const float*)d_in[2];
    const float* Wd = (const float*)d_in[3];
    const float* bd = (const float*)d_in[4];
    const float* Wc = (const float*)d_in[5];
    const float* bc = (const float*)d_in[6];
    const int*   s  = (const int*)d_in[7];
    const int*   pv = (const int*)d_in[8];

    char* ws = (char*)d_ws;
    float* accf = (float*)ws;                 // [0]=mse_sum, [1]=pair total
    int*   acci = (int*)ws;                   // [2]=nP, [3]=nR
    unsigned short* gbf = (unsigned short*)(ws + 256);                  // 16384*256 bf16 = 8 MB
    unsigned short* WeT = (unsigned short*)(ws + 256 + (size_t)NR * NH * 2);
    unsigned short* WdT = WeT + (size_t)NH * NF;
    float* cvec = (float*)(WdT + (size_t)NF * NH);
    float* cP = cvec + NR;
    float* cR = cP + NR;

    hipMemsetAsync(d_ws, 0, 256, stream);
    prep_kernel<<<2048, 256, 0, stream>>>(We, Wd, WeT, WdT);
    gemm1_kernel<<<dim3(128, 2), 256, 0, stream>>>(X, WeT, be, gbf);
    c_kernel<<<4096, 256, 0, stream>>>(gbf, Wc, bc, cvec);
    compact_kernel<<<64, 256, 0, stream>>>(cvec, s, pv, cP, cR, acci + 2);
    pair_kernel<<<dim3(16, 64), 256, 0, stream>>>(cP, cR, acci + 2, accf + 1);
    gemm2_kernel<<<dim3(128, 8), 256, 0, stream>>>(gbf, WdT, bd, X, accf);
    finalize_kernel<<<1, 1, 0, stream>>>(accf, acci, (float*)d_out);
}